// Round 1
// baseline (265.941 us; speedup 1.0000x reference)
//
#include <hip/hip_runtime.h>
#include <stdint.h>

// GPTQ 4-bit fused dequant-GEMM, MI355X gfx950.
// M=128, K=4096, N=11008, group=128 along K, g_idx[k] = k>>7 (affine).
//
// Structure (round 1):
//  k_cvt_x : x fp32 -> bf16 into ws (1 MB)
//  k_zs    : zs[g][n] = (unpacked_zero+1)*scale  (fp32, 1.375 MB in ws)
//  k_gemm  : BM=128 x BN=64 block, 4 waves (2x2) of 64x32, 16x16x32 bf16 MFMA.
//            A (x) staged in LDS, XOR-swizzled; B (W) dequantized DIRECTLY into
//            MFMA fragments: one int32 of qweight == one lane's 8-k fragment.

#define M_DIM 128
#define K_DIM 4096
#define N_DIM 11008
#define GS    128
#define NG    32

typedef __attribute__((ext_vector_type(8))) __bf16 bf16x8;
typedef __attribute__((ext_vector_type(4))) __bf16 bf16x4;
typedef __attribute__((ext_vector_type(4))) float  f32x4;

// ---------------- pre-kernel 1: x fp32 -> bf16 ----------------
__global__ void k_cvt_x(const float* __restrict__ x, __bf16* __restrict__ xb) {
    int i = (blockIdx.x * 256 + threadIdx.x) * 4;   // grid 512*256*4 == 524288 exact
    float4 v = *(const float4*)(x + i);
    bf16x4 o;
    o[0] = (__bf16)v.x; o[1] = (__bf16)v.y; o[2] = (__bf16)v.z; o[3] = (__bf16)v.w;
    *(bf16x4*)(xb + i) = o;
}

// ---------------- pre-kernel 2: zs[g][n] = (z+1)*scale ----------------
__global__ void k_zs(const int* __restrict__ qzeros, const float* __restrict__ scales,
                     float* __restrict__ zs) {
    int n = blockIdx.x * 256 + threadIdx.x;   // grid.x = 43 (43*256 == 11008 exact)
    int g = blockIdx.y;                       // 32
    unsigned qz = (unsigned)qzeros[g * (N_DIM / 8) + (n >> 3)];
    float z = (float)((qz >> ((n & 7) * 4)) & 15u) + 1.0f;
    zs[g * N_DIM + n] = z * scales[g * N_DIM + n];
}

// ---------------- main fused kernel ----------------
__global__ __launch_bounds__(256, 1)
void k_gemm(const __bf16* __restrict__ xb,      // [128][4096] bf16
            const int*    __restrict__ qweight, // [512][11008] int32
            const float*  __restrict__ scales,  // [32][11008]
            const float*  __restrict__ zst,     // [32][11008]  (z+1)*scale
            const float*  __restrict__ bias,    // [11008]
            float*        __restrict__ out)     // [128][11008]
{
    // A tile for one group: 128 rows x 128 k, XOR-swizzled in 16B (8-elem) blocks:
    // logical (m, kb) stored at As[m*128 + (kb ^ (m&15))*8 .. +8]
    __shared__ __bf16 As[128 * 128];   // 32 KB

    const int tid  = threadIdx.x;
    const int lane = tid & 63;
    const int w    = tid >> 6;
    const int wy   = w >> 1;     // m-offset 64*wy
    const int wx   = w & 1;      // n-offset 32*wx
    const int q    = lane >> 4;  // quad 0..3
    const int lr   = lane & 15;

    const int n0 = blockIdx.x * 64;
    int ncol[2];
    ncol[0] = n0 + wx * 32 + lr;
    ncol[1] = ncol[0] + 16;

    f32x4 acc[4][2];
#pragma unroll
    for (int f = 0; f < 4; ++f)
#pragma unroll
        for (int h = 0; h < 2; ++h)
            acc[f][h] = (f32x4){0.f, 0.f, 0.f, 0.f};

    // ---- staging prefetch (group 0): 2048 16B chunks, 8 per thread ----
    uint4 pre[8];
#pragma unroll
    for (int it = 0; it < 8; ++it) {
        int c = it * 256 + tid;
        int m = c >> 4, kb2 = c & 15;
        int kb = kb2 ^ (m & 15);
        pre[it] = *(const uint4*)(xb + m * K_DIM + kb * 8);
    }

    for (int g = 0; g < NG; ++g) {
        __syncthreads();   // previous group's LDS reads complete
#pragma unroll
        for (int it = 0; it < 8; ++it) {
            int c = it * 256 + tid;
            int m = c >> 4, kb2 = c & 15;
            *(uint4*)(&As[m * 128 + kb2 * 8]) = pre[it];
        }
        __syncthreads();   // A tile ready

        if (g + 1 < NG) {  // prefetch next group's A while computing this one
#pragma unroll
            for (int it = 0; it < 8; ++it) {
                int c = it * 256 + tid;
                int m = c >> 4, kb2 = c & 15;
                int kb = kb2 ^ (m & 15);
                pre[it] = *(const uint4*)(xb + m * K_DIM + (g + 1) * GS + kb * 8);
            }
        }

        float sc[2], zz[2];
#pragma unroll
        for (int h = 0; h < 2; ++h) {
            sc[h] = scales[g * N_DIM + ncol[h]];
            zz[h] = zst[g * N_DIM + ncol[h]];
        }

#pragma unroll
        for (int kk = 0; kk < 4; ++kk) {
            // ---- B fragments: one int32 == one lane's 8-k fragment ----
            bf16x8 bf[2];
#pragma unroll
            for (int h = 0; h < 2; ++h) {
                unsigned qw = (unsigned)qweight[(g * 16 + kk * 4 + q) * N_DIM + ncol[h]];
#pragma unroll
                for (int j = 0; j < 8; ++j) {
                    float wv = fmaf((float)((qw >> (4 * j)) & 15u), sc[h], -zz[h]);
                    bf[h][j] = (__bf16)wv;
                }
            }
            // ---- A fragments from LDS + MFMA ----
#pragma unroll
            for (int f = 0; f < 4; ++f) {
                int m   = wy * 64 + f * 16 + lr;
                int kb2 = (kk * 4 + q) ^ lr;      // m&15 == lr
                bf16x8 af = *(const bf16x8*)(&As[m * 128 + kb2 * 8]);
#pragma unroll
                for (int h = 0; h < 2; ++h)
                    acc[f][h] = __builtin_amdgcn_mfma_f32_16x16x32_bf16(af, bf[h], acc[f][h], 0, 0, 0);
            }
        }
    }

    // ---- epilogue: D[row=(lane>>4)*4+r][col=lane&15], + bias ----
    float bv[2] = { bias[ncol[0]], bias[ncol[1]] };
#pragma unroll
    for (int f = 0; f < 4; ++f) {
        int mrow = wy * 64 + f * 16 + q * 4;
#pragma unroll
        for (int h = 0; h < 2; ++h)
#pragma unroll
            for (int r = 0; r < 4; ++r)
                out[(size_t)(mrow + r) * N_DIM + ncol[h]] = acc[f][h][r] + bv[h];
    }
}

extern "C" void kernel_launch(void* const* d_in, const int* in_sizes, int n_in,
                              void* d_out, int out_size, void* d_ws, size_t ws_size,
                              hipStream_t stream) {
    const float* x       = (const float*)d_in[0];
    const int*   qweight = (const int*)d_in[1];
    const int*   qzeros  = (const int*)d_in[2];
    const float* scales  = (const float*)d_in[3];
    const float* bias    = (const float*)d_in[4];
    // d_in[5] = g_idx, affine by construction (g = k >> 7) -> unused

    __bf16* xb  = (__bf16*)d_ws;                                    // 1 MB
    float*  zst = (float*)((char*)d_ws + (size_t)M_DIM * K_DIM * 2); // 1.375 MB

    k_cvt_x<<<dim3(512),     dim3(256), 0, stream>>>(x, xb);
    k_zs   <<<dim3(43, 32),  dim3(256), 0, stream>>>(qzeros, scales, zst);
    k_gemm <<<dim3(N_DIM/64), dim3(256), 0, stream>>>(xb, qweight, scales, zst, bias, (float*)d_out);
}

// Round 3
// 211.135 us; speedup vs baseline: 1.2596x; 1.2596x over previous
//
#include <hip/hip_runtime.h>
#include <stdint.h>

// GPTQ 4-bit fused dequant-GEMM, MI355X gfx950.  Round 3.
// M=128, K=4096, N=11008, group=128, g_idx[k]=k>>7 (affine).
//
// Round 2 failed absmax 0.535 (threshold 0.29): merged f16 magic constant
// -(1024*s + z1) ~= -10.24 has ulp 0.0078 -> ~0.004 abs error per weight via
// catastrophic cancellation.  Round 3 fix: exact packed subtract of the 0x6400
// bias ((1024+q)-1024 and (1024+16q)-1024 are EXACT in f16), then fma against
// small constants {s, s/16} and -z1.  Per-weight error ~1e-4.
// Structure otherwise identical to round 2:
//  * split-K x4, grid (172,4); fp32 unsafeAtomicAdd onto bias-initialized out
//  * 512-thread blocks, 8 waves of 32x32 tiles
//  * register prefetch of next group's A-staging/qweight/scales during compute

#define M_DIM 128
#define K_DIM 4096
#define N_DIM 11008
#define GS    128
#define NG    32
#define SPLIT 4
#define GPB   (NG / SPLIT)   // 8 groups per block

typedef _Float16 half8  __attribute__((ext_vector_type(8)));
typedef _Float16 half2t __attribute__((ext_vector_type(2)));
typedef _Float16 half4t __attribute__((ext_vector_type(4)));
typedef float    f32x4  __attribute__((ext_vector_type(4)));

// ---------------- pre-kernel 1: x fp32 -> f16 ----------------
__global__ void k_cvt_x(const float* __restrict__ x, _Float16* __restrict__ xh) {
    int i = (blockIdx.x * 256 + threadIdx.x) * 4;   // 512 blocks * 1024 = 524288 exact
    float4 v = *(const float4*)(x + i);
    half4t o;
    o[0] = (_Float16)v.x; o[1] = (_Float16)v.y; o[2] = (_Float16)v.z; o[3] = (_Float16)v.w;
    *(half4t*)(xh + i) = o;
}

// ---------------- pre-kernel 2: zs[g][n] = (z+1)*scale (fp32) ----------------
__global__ void k_zs(const int* __restrict__ qzeros, const float* __restrict__ scales,
                     float* __restrict__ zs) {
    int n = blockIdx.x * 256 + threadIdx.x;   // 43*256 == 11008 exact
    int g = blockIdx.y;                       // 32
    unsigned qz = (unsigned)qzeros[g * (N_DIM / 8) + (n >> 3)];
    float z = (float)((qz >> ((n & 7) * 4)) & 15u) + 1.0f;
    zs[g * N_DIM + n] = z * scales[g * N_DIM + n];
}

// ---------------- pre-kernel 3: out[m][n] = bias[n] ----------------
__global__ void k_init(const float* __restrict__ bias, float* __restrict__ out) {
    int i = (blockIdx.x * 256 + threadIdx.x) * 4;   // 1376 blocks: 128*11008 exact
    int n = i % N_DIM;                              // N_DIM % 4 == 0
    *(float4*)(out + i) = *(const float4*)(bias + n);
}

// nibble pair p (nibbles 2p, 2p+1) of q -> two f16 weights:
//  t = {0x6400|nib_lo, 0x6400|nib_hi<<4} = {1024+q_lo, 1024+16*q_hi}
//  qf = t - 1024           (EXACT in f16: integers <= 2048)
//  w  = fma(qf, {s, s/16}, {-z1, -z1})   where z1 = (z+1)*s
__device__ __forceinline__ half8 dequant8(unsigned q, half2t S2, half2t Z2) {
    const half2t BIAS = __builtin_bit_cast(half2t, 0x64006400u);
    uint4 fr;
    unsigned* fp = (unsigned*)&fr;
#pragma unroll
    for (int p = 0; p < 4; ++p) {
        unsigned r = __builtin_amdgcn_perm(q, q, 0x00010001u * (unsigned)p); // byte p -> bytes 0,2
        unsigned t = (r & 0x00F0000Fu) | 0x64006400u;                        // v_and_or_b32
        half2t qf = __builtin_bit_cast(half2t, t) - BIAS;                    // exact {q, 16q}
        half2t w2 = __builtin_elementwise_fma(qf, S2, Z2);
        fp[p] = __builtin_bit_cast(unsigned, w2);
    }
    return __builtin_bit_cast(half8, fr);
}

// ---------------- main fused kernel ----------------
__global__ __launch_bounds__(512, 4)
void k_gemm(const _Float16* __restrict__ xh,     // [128][4096] f16
            const int*      __restrict__ qweight,// [512][11008] int32
            const float*    __restrict__ scales, // [32][11008]
            const float*    __restrict__ zst,    // [32][11008] (z+1)*s
            float*          __restrict__ out)    // [128][11008], pre-set to bias
{
    // A tile for one group: 128 m x 128 k, XOR-swizzled 16B blocks:
    // logical (m,kb) at As[m*128 + (kb ^ (m&15))*8]
    __shared__ _Float16 As[128 * 128];   // 32 KB

    const int tid  = threadIdx.x;
    const int lane = tid & 63;
    const int w    = tid >> 6;    // 0..7
    const int wy   = w >> 1;      // m offset 32*wy
    const int wx   = w & 1;       // n offset 32*wx
    const int q    = lane >> 4;   // quad
    const int lr   = lane & 15;

    const int n0 = blockIdx.x * 64;
    const int g0 = blockIdx.y * GPB;
    int ncol[2] = { n0 + wx * 32 + lr, n0 + wx * 32 + lr + 16 };

    f32x4 acc[2][2];
#pragma unroll
    for (int f = 0; f < 2; ++f)
#pragma unroll
        for (int h = 0; h < 2; ++h)
            acc[f][h] = (f32x4){0.f, 0.f, 0.f, 0.f};

    // ---- prefetch group g0: A staging (4 x 16B/thread), qweight (8/lane), scales ----
    uint4 pre[4];
#pragma unroll
    for (int it = 0; it < 4; ++it) {
        int c = it * 512 + tid;
        int m = c >> 4, kb2 = c & 15;
        int kb = kb2 ^ (m & 15);
        pre[it] = *(const uint4*)(xh + (size_t)m * K_DIM + g0 * GS + kb * 8);
    }
    unsigned qwn[8];
    float scn[2], zcn[2];
#pragma unroll
    for (int kk = 0; kk < 4; ++kk)
#pragma unroll
        for (int h = 0; h < 2; ++h)
            qwn[kk * 2 + h] = (unsigned)qweight[(size_t)(g0 * 16 + kk * 4 + q) * N_DIM + ncol[h]];
#pragma unroll
    for (int h = 0; h < 2; ++h) {
        scn[h] = scales[(size_t)g0 * N_DIM + ncol[h]];
        zcn[h] = zst[(size_t)g0 * N_DIM + ncol[h]];
    }

    for (int g = 0; g < GPB; ++g) {
        // rotate next -> cur
        uint4 cur[4];
        unsigned qw[8];
        float sc[2], zc[2];
#pragma unroll
        for (int it = 0; it < 4; ++it) cur[it] = pre[it];
#pragma unroll
        for (int i = 0; i < 8; ++i) qw[i] = qwn[i];
#pragma unroll
        for (int h = 0; h < 2; ++h) { sc[h] = scn[h]; zc[h] = zcn[h]; }

        __syncthreads();   // previous group's LDS reads done
#pragma unroll
        for (int it = 0; it < 4; ++it) {
            int c = it * 512 + tid;
            int m = c >> 4, kb2 = c & 15;
            *(uint4*)(&As[m * 128 + kb2 * 8]) = cur[it];
        }
        __syncthreads();   // A tile ready

        if (g + 1 < GPB) {   // issue next group's prefetches NOW, overlap with compute
            int gn = g0 + g + 1;
#pragma unroll
            for (int it = 0; it < 4; ++it) {
                int c = it * 512 + tid;
                int m = c >> 4, kb2 = c & 15;
                int kb = kb2 ^ (m & 15);
                pre[it] = *(const uint4*)(xh + (size_t)m * K_DIM + gn * GS + kb * 8);
            }
#pragma unroll
            for (int kk = 0; kk < 4; ++kk)
#pragma unroll
                for (int h = 0; h < 2; ++h)
                    qwn[kk * 2 + h] = (unsigned)qweight[(size_t)(gn * 16 + kk * 4 + q) * N_DIM + ncol[h]];
#pragma unroll
            for (int h = 0; h < 2; ++h) {
                scn[h] = scales[(size_t)gn * N_DIM + ncol[h]];
                zcn[h] = zst[(size_t)gn * N_DIM + ncol[h]];
            }
        }

        // per-(group,h) dequant constants: S2={s, s/16}, Z2={-z1, -z1}
        half2t S2[2], Z2[2];
#pragma unroll
        for (int h = 0; h < 2; ++h) {
            float s = sc[h], z1 = zc[h];
            S2[h][0] = (_Float16)s;
            S2[h][1] = (_Float16)(s * 0.0625f);
            Z2[h][0] = (_Float16)(-z1);
            Z2[h][1] = (_Float16)(-z1);
        }

#pragma unroll
        for (int kk = 0; kk < 4; ++kk) {
            half8 bf[2];
#pragma unroll
            for (int h = 0; h < 2; ++h)
                bf[h] = dequant8(qw[kk * 2 + h], S2[h], Z2[h]);
#pragma unroll
            for (int f = 0; f < 2; ++f) {
                int m   = wy * 32 + f * 16 + lr;
                int kb2 = (kk * 4 + q) ^ lr;     // m&15 == lr
                half8 af = *(const half8*)(&As[m * 128 + kb2 * 8]);
#pragma unroll
                for (int h = 0; h < 2; ++h)
                    acc[f][h] = __builtin_amdgcn_mfma_f32_16x16x32_f16(af, bf[h], acc[f][h], 0, 0, 0);
            }
        }
    }

    // ---- epilogue: atomic-accumulate into bias-initialized out ----
#pragma unroll
    for (int f = 0; f < 2; ++f) {
        int mrow = wy * 32 + f * 16 + q * 4;
#pragma unroll
        for (int h = 0; h < 2; ++h)
#pragma unroll
            for (int r = 0; r < 4; ++r)
                unsafeAtomicAdd(&out[(size_t)(mrow + r) * N_DIM + ncol[h]], acc[f][h][r]);
    }
}

extern "C" void kernel_launch(void* const* d_in, const int* in_sizes, int n_in,
                              void* d_out, int out_size, void* d_ws, size_t ws_size,
                              hipStream_t stream) {
    const float* x       = (const float*)d_in[0];
    const int*   qweight = (const int*)d_in[1];
    const int*   qzeros  = (const int*)d_in[2];
    const float* scales  = (const float*)d_in[3];
    const float* bias    = (const float*)d_in[4];
    // d_in[5] = g_idx, affine by construction -> unused

    _Float16* xh  = (_Float16*)d_ws;                                   // 1 MB
    float*    zst = (float*)((char*)d_ws + (size_t)M_DIM * K_DIM * 2); // 1.375 MB

    k_cvt_x<<<dim3(512),            dim3(256), 0, stream>>>(x, xh);
    k_zs   <<<dim3(43, 32),         dim3(256), 0, stream>>>(qzeros, scales, zst);
    k_init <<<dim3(1376),           dim3(256), 0, stream>>>(bias, (float*)d_out);
    k_gemm <<<dim3(N_DIM/64, SPLIT), dim3(512), 0, stream>>>(xh, qweight, scales, zst, (float*)d_out);
}

// Round 4
// 200.805 us; speedup vs baseline: 1.3244x; 1.0514x over previous
//
#include <hip/hip_runtime.h>
#include <stdint.h>

// GPTQ 4-bit fused dequant-GEMM, MI355X gfx950.  Round 4.
// M=128, K=4096, N=11008, group=128, g_idx[k]=k>>7 (affine).
//
// Round 3 was atomic-write-bound: 5.6M scalar fp32 device atomics -> 304 MB
// of HBM write traffic (each 4B atomic ~ a 64B memory-side transaction,
// 4-way split contention), 2.6 TB/s, 136 us.  Round 4: split-K partials go
// to per-split ws buffers with plain coalesced stores (22.5 MB total); a
// reduce kernel does out = bias + sum(partials).  k_cvt_x/k_zs merged into
// one prep kernel; k_init deleted.  3 dispatches.
// GEMM structure (unchanged from R3): grid (172,4), 512 thr / 8 waves of
// 32x32, f16 MFMA 16x16x32, exact-cancellation magic-number dequant,
// XOR-swizzled LDS A tile, register prefetch of next group.

#define M_DIM 128
#define K_DIM 4096
#define N_DIM 11008
#define GS    128
#define NG    32
#define SPLIT 4
#define GPB   (NG / SPLIT)   // 8 groups per block
#define PART_STRIDE ((size_t)M_DIM * N_DIM)

typedef _Float16 half8  __attribute__((ext_vector_type(8)));
typedef _Float16 half2t __attribute__((ext_vector_type(2)));
typedef _Float16 half4t __attribute__((ext_vector_type(4)));
typedef float    f32x4  __attribute__((ext_vector_type(4)));

// ---------------- prep: blocks 0..511 cvt x->f16; 512..1887 zs=(z+1)*s ----
__global__ void k_prep(const float* __restrict__ x, const int* __restrict__ qzeros,
                       const float* __restrict__ scales,
                       _Float16* __restrict__ xh, float* __restrict__ zs) {
    int b = blockIdx.x, tid = threadIdx.x;
    if (b < 512) {                                   // 512*256*4 == 524288 exact
        int i = (b * 256 + tid) * 4;
        float4 v = *(const float4*)(x + i);
        half4t o;
        o[0] = (_Float16)v.x; o[1] = (_Float16)v.y;
        o[2] = (_Float16)v.z; o[3] = (_Float16)v.w;
        *(half4t*)(xh + i) = o;
    } else {                                         // 1376 blocks: 32 g x 43 nb
        b -= 512;
        int g = b / 43;
        int n = (b - g * 43) * 256 + tid;            // 43*256 == 11008 exact
        unsigned qz = (unsigned)qzeros[g * (N_DIM / 8) + (n >> 3)];
        float z = (float)((qz >> ((n & 7) * 4)) & 15u) + 1.0f;
        zs[g * N_DIM + n] = z * scales[g * N_DIM + n];
    }
}

// nibble pair p (nibbles 2p, 2p+1) of q -> two f16 weights:
//  t  = {0x6400|nib_lo, 0x6400|nib_hi<<4} = {1024+q_lo, 1024+16*q_hi}
//  qf = t - 1024                  (EXACT in f16: integers <= 2048)
//  w  = fma(qf, {s, s/16}, {-z1}) where z1 = (z+1)*s
__device__ __forceinline__ half8 dequant8(unsigned q, half2t S2, half2t Z2) {
    const half2t BIAS = __builtin_bit_cast(half2t, 0x64006400u);
    uint4 fr;
    unsigned* fp = (unsigned*)&fr;
#pragma unroll
    for (int p = 0; p < 4; ++p) {
        unsigned r = __builtin_amdgcn_perm(q, q, 0x00010001u * (unsigned)p); // byte p -> bytes 0,2
        unsigned t = (r & 0x00F0000Fu) | 0x64006400u;                        // v_and_or_b32
        half2t qf = __builtin_bit_cast(half2t, t) - BIAS;                    // exact {q, 16q}
        half2t w2 = __builtin_elementwise_fma(qf, S2, Z2);
        fp[p] = __builtin_bit_cast(unsigned, w2);
    }
    return __builtin_bit_cast(half8, fr);
}

// ---------------- main fused kernel ----------------
__global__ __launch_bounds__(512, 4)
void k_gemm(const _Float16* __restrict__ xh,     // [128][4096] f16
            const int*      __restrict__ qweight,// [512][11008] int32
            const float*    __restrict__ scales, // [32][11008]
            const float*    __restrict__ zst,    // [32][11008] (z+1)*s
            float*          __restrict__ part)   // [SPLIT][128][11008] partials
{
    // A tile for one group: 128 m x 128 k, XOR-swizzled 16B blocks:
    // logical (m,kb) at As[m*128 + (kb ^ (m&15))*8]
    __shared__ _Float16 As[128 * 128];   // 32 KB

    const int tid  = threadIdx.x;
    const int lane = tid & 63;
    const int w    = tid >> 6;    // 0..7
    const int wy   = w >> 1;      // m offset 32*wy
    const int wx   = w & 1;       // n offset 32*wx
    const int q    = lane >> 4;   // quad
    const int lr   = lane & 15;

    const int n0 = blockIdx.x * 64;
    const int g0 = blockIdx.y * GPB;
    int ncol[2] = { n0 + wx * 32 + lr, n0 + wx * 32 + lr + 16 };

    f32x4 acc[2][2];
#pragma unroll
    for (int f = 0; f < 2; ++f)
#pragma unroll
        for (int h = 0; h < 2; ++h)
            acc[f][h] = (f32x4){0.f, 0.f, 0.f, 0.f};

    // ---- prefetch group g0: A staging (4 x 16B/thread), qweight (8/lane), scales ----
    uint4 pre[4];
#pragma unroll
    for (int it = 0; it < 4; ++it) {
        int c = it * 512 + tid;
        int m = c >> 4, kb2 = c & 15;
        int kb = kb2 ^ (m & 15);
        pre[it] = *(const uint4*)(xh + (size_t)m * K_DIM + g0 * GS + kb * 8);
    }
    unsigned qwn[8];
    float scn[2], zcn[2];
#pragma unroll
    for (int kk = 0; kk < 4; ++kk)
#pragma unroll
        for (int h = 0; h < 2; ++h)
            qwn[kk * 2 + h] = (unsigned)qweight[(size_t)(g0 * 16 + kk * 4 + q) * N_DIM + ncol[h]];
#pragma unroll
    for (int h = 0; h < 2; ++h) {
        scn[h] = scales[(size_t)g0 * N_DIM + ncol[h]];
        zcn[h] = zst[(size_t)g0 * N_DIM + ncol[h]];
    }

    for (int g = 0; g < GPB; ++g) {
        // rotate next -> cur
        uint4 cur[4];
        unsigned qw[8];
        float sc[2], zc[2];
#pragma unroll
        for (int it = 0; it < 4; ++it) cur[it] = pre[it];
#pragma unroll
        for (int i = 0; i < 8; ++i) qw[i] = qwn[i];
#pragma unroll
        for (int h = 0; h < 2; ++h) { sc[h] = scn[h]; zc[h] = zcn[h]; }

        __syncthreads();   // previous group's LDS reads done
#pragma unroll
        for (int it = 0; it < 4; ++it) {
            int c = it * 512 + tid;
            int m = c >> 4, kb2 = c & 15;
            *(uint4*)(&As[m * 128 + kb2 * 8]) = cur[it];
        }
        __syncthreads();   // A tile ready

        if (g + 1 < GPB) {   // issue next group's prefetches NOW, overlap with compute
            int gn = g0 + g + 1;
#pragma unroll
            for (int it = 0; it < 4; ++it) {
                int c = it * 512 + tid;
                int m = c >> 4, kb2 = c & 15;
                int kb = kb2 ^ (m & 15);
                pre[it] = *(const uint4*)(xh + (size_t)m * K_DIM + gn * GS + kb * 8);
            }
#pragma unroll
            for (int kk = 0; kk < 4; ++kk)
#pragma unroll
                for (int h = 0; h < 2; ++h)
                    qwn[kk * 2 + h] = (unsigned)qweight[(size_t)(gn * 16 + kk * 4 + q) * N_DIM + ncol[h]];
#pragma unroll
            for (int h = 0; h < 2; ++h) {
                scn[h] = scales[(size_t)gn * N_DIM + ncol[h]];
                zcn[h] = zst[(size_t)gn * N_DIM + ncol[h]];
            }
        }

        // per-(group,h) dequant constants: S2={s, s/16}, Z2={-z1, -z1}
        half2t S2[2], Z2[2];
#pragma unroll
        for (int h = 0; h < 2; ++h) {
            float s = sc[h], z1 = zc[h];
            S2[h][0] = (_Float16)s;
            S2[h][1] = (_Float16)(s * 0.0625f);
            Z2[h][0] = (_Float16)(-z1);
            Z2[h][1] = (_Float16)(-z1);
        }

#pragma unroll
        for (int kk = 0; kk < 4; ++kk) {
            half8 bf[2];
#pragma unroll
            for (int h = 0; h < 2; ++h)
                bf[h] = dequant8(qw[kk * 2 + h], S2[h], Z2[h]);
#pragma unroll
            for (int f = 0; f < 2; ++f) {
                int m   = wy * 32 + f * 16 + lr;
                int kb2 = (kk * 4 + q) ^ lr;     // m&15 == lr
                half8 af = *(const half8*)(&As[m * 128 + kb2 * 8]);
#pragma unroll
                for (int h = 0; h < 2; ++h)
                    acc[f][h] = __builtin_amdgcn_mfma_f32_16x16x32_f16(af, bf[h], acc[f][h], 0, 0, 0);
            }
        }
    }

    // ---- epilogue: plain coalesced stores to this split's partial buffer ----
    float* po = part + (size_t)blockIdx.y * PART_STRIDE;
#pragma unroll
    for (int f = 0; f < 2; ++f) {
        int mrow = wy * 32 + f * 16 + q * 4;
#pragma unroll
        for (int h = 0; h < 2; ++h)
#pragma unroll
            for (int r = 0; r < 4; ++r)
                po[(size_t)(mrow + r) * N_DIM + ncol[h]] = acc[f][h][r];
    }
}

// ---------------- reduce: out = bias + sum_s part[s] ----------------
__global__ void k_reduce(const float* __restrict__ part, const float* __restrict__ bias,
                         float* __restrict__ out) {
    int i = (blockIdx.x * 256 + threadIdx.x) * 4;   // 1376 blocks: 128*11008 exact
    int m = i / N_DIM;                               // magic-div
    int n = i - m * N_DIM;                           // N_DIM%4==0 -> n%4==0
    f32x4 s = *(const f32x4*)(bias + n);
#pragma unroll
    for (int sp = 0; sp < SPLIT; ++sp)
        s += *(const f32x4*)(part + sp * PART_STRIDE + i);
    *(f32x4*)(out + i) = s;
}

extern "C" void kernel_launch(void* const* d_in, const int* in_sizes, int n_in,
                              void* d_out, int out_size, void* d_ws, size_t ws_size,
                              hipStream_t stream) {
    const float* x       = (const float*)d_in[0];
    const int*   qweight = (const int*)d_in[1];
    const int*   qzeros  = (const int*)d_in[2];
    const float* scales  = (const float*)d_in[3];
    const float* bias    = (const float*)d_in[4];
    // d_in[5] = g_idx, affine by construction -> unused

    char* ws = (char*)d_ws;
    _Float16* xh   = (_Float16*)ws;                              // 1,048,576 B
    float*    zst  = (float*)(ws + 1048576);                     // 1,409,024 B
    float*    part = (float*)(ws + 1048576 + 1409024);           // 4 x 5,636,096 B

    k_prep  <<<dim3(1888),            dim3(256), 0, stream>>>(x, qzeros, scales, xh, zst);
    k_gemm  <<<dim3(N_DIM/64, SPLIT), dim3(512), 0, stream>>>(xh, qweight, scales, zst, part);
    k_reduce<<<dim3(1376),            dim3(256), 0, stream>>>(part, bias, (float*)d_out);
}

// Round 5
// 107.883 us; speedup vs baseline: 2.4651x; 1.8613x over previous
//
#include <hip/hip_runtime.h>
#include <stdint.h>

// GPTQ 4-bit fused dequant-GEMM, MI355X gfx950.  Round 5.
// M=128, K=4096, N=11008, group=128, g_idx[k]=k>>7 (affine).
//
// Round 3/4 post-mortem: identical 305 MB WRITE_SIZE across two different
// epilogues (atomics vs plain stores) -> the writes were SCRATCH, not output.
// dequant8 wrote its result through a casted pointer (unsigned*)&fr, defeating
// SROA; the 16B temp lived in private memory -> ~700 MB of scratch round-trips
// + ~200cyc serialized latency per dequant (VGPR_Count 44, MfmaUtil 3.3%).
// Round 5:
//  * dequant8 rebuilt with __builtin_shufflevector only (no pointer casts).
//  * A-tile staged via __builtin_amdgcn_global_load_lds (16B/lane, async,
//    un-sinkable) into a DOUBLE-BUFFERED LDS tile (2 x 32 KB = 64 KB).
//    LDS dest = chunk*16 bytes (wave-uniform base + lane*16: constraint OK);
//    the XOR swizzle is applied on the GLOBAL address side.
//  * one __syncthreads per group; next group's A + qweight issued right after
//    the barrier, in flight under the whole compute phase.
// Unchanged: split-K x4 -> partials in ws + reduce(bias) kernel; 512 thr,
// 8 waves of 32x32, f16 MFMA 16x16x32, exact-cancellation magic dequant.

#define M_DIM 128
#define K_DIM 4096
#define N_DIM 11008
#define GS    128
#define NG    32
#define SPLIT 4
#define GPB   (NG / SPLIT)   // 8 groups per block
#define PART_STRIDE ((size_t)M_DIM * N_DIM)

typedef _Float16 half8  __attribute__((ext_vector_type(8)));
typedef _Float16 half2t __attribute__((ext_vector_type(2)));
typedef _Float16 half4t __attribute__((ext_vector_type(4)));
typedef float    f32x4  __attribute__((ext_vector_type(4)));

// ---------------- prep: blocks 0..511 cvt x->f16; 512..1887 zs=(z+1)*s ----
__global__ void k_prep(const float* __restrict__ x, const int* __restrict__ qzeros,
                       const float* __restrict__ scales,
                       _Float16* __restrict__ xh, float* __restrict__ zs) {
    int b = blockIdx.x, tid = threadIdx.x;
    if (b < 512) {                                   // 512*256*4 == 524288 exact
        int i = (b * 256 + tid) * 4;
        float4 v = *(const float4*)(x + i);
        half4t o;
        o[0] = (_Float16)v.x; o[1] = (_Float16)v.y;
        o[2] = (_Float16)v.z; o[3] = (_Float16)v.w;
        *(half4t*)(xh + i) = o;
    } else {                                         // 1376 blocks: 32 g x 43 nb
        b -= 512;
        int g = b / 43;
        int n = (b - g * 43) * 256 + tid;            // 43*256 == 11008 exact
        unsigned qz = (unsigned)qzeros[g * (N_DIM / 8) + (n >> 3)];
        float z = (float)((qz >> ((n & 7) * 4)) & 15u) + 1.0f;
        zs[g * N_DIM + n] = z * scales[g * N_DIM + n];
    }
}

// async 16B/lane global->LDS.  lds base must be wave-uniform; lane i's 16B
// lands at base + i*16.
__device__ __forceinline__ void load_lds16(const void* g, void* l) {
    __builtin_amdgcn_global_load_lds(
        (const __attribute__((address_space(1))) unsigned int*)g,
        (__attribute__((address_space(3))) unsigned int*)l, 16, 0, 0);
}

// nibble pair p (nibbles 2p, 2p+1) of q -> two f16 weights:
//  t  = {0x6400|nib_lo, 0x6400|nib_hi<<4} = {1024+q_lo, 1024+16*q_hi}
//  qf = t - 1024                  (EXACT in f16: integers <= 2048)
//  w  = fma(qf, {s, s/16}, {-z1}) where z1 = (z+1)*s
// No pointer casts anywhere: pure vector ops, SROA-safe.
__device__ __forceinline__ half8 dequant8(unsigned q, half2t S2, half2t Z2) {
    const half2t BIAS = __builtin_bit_cast(half2t, 0x64006400u);
    half2t w[4];
#pragma unroll
    for (int p = 0; p < 4; ++p) {
        unsigned r = __builtin_amdgcn_perm(q, q, 0x00010001u * (unsigned)p); // byte p -> bytes 0,2
        unsigned t = (r & 0x00F0000Fu) | 0x64006400u;                        // v_and_or_b32
        w[p] = __builtin_elementwise_fma(__builtin_bit_cast(half2t, t) - BIAS, S2, Z2);
    }
    half4t lo = __builtin_shufflevector(w[0], w[1], 0, 1, 2, 3);
    half4t hi = __builtin_shufflevector(w[2], w[3], 0, 1, 2, 3);
    return __builtin_shufflevector(lo, hi, 0, 1, 2, 3, 4, 5, 6, 7);
}

// ---------------- main fused kernel ----------------
__global__ __launch_bounds__(512, 4)
void k_gemm(const _Float16* __restrict__ xh,     // [128][4096] f16
            const int*      __restrict__ qweight,// [512][11008] int32
            const float*    __restrict__ scales, // [32][11008]
            const float*    __restrict__ zst,    // [32][11008] (z+1)*s
            float*          __restrict__ part)   // [SPLIT][128][11008] partials
{
    // Double-buffered A tile: logical (m,kb) of buffer b at
    //   As[b][m*128 + (kb ^ (m&15))*8]   (halfs; *2 = bytes)
    // Staged so that chunk c (c = it*512 + tid) lands at byte offset c*16:
    //   c*16 == m*256 + (c&15)*16 with m=c>>4 and (c&15) == kb^(m&15).
    __shared__ _Float16 As[2][128 * 128];   // 2 x 32 KB = 64 KB

    const int tid  = threadIdx.x;
    const int lane = tid & 63;
    const int w    = tid >> 6;    // 0..7
    const int wy   = w >> 1;      // m offset 32*wy
    const int wx   = w & 1;       // n offset 32*wx
    const int q    = lane >> 4;   // quad
    const int lr   = lane & 15;

    const int n0 = blockIdx.x * 64;
    const int g0 = blockIdx.y * GPB;
    int ncol[2] = { n0 + wx * 32 + lr, n0 + wx * 32 + lr + 16 };

    f32x4 acc[2][2];
#pragma unroll
    for (int f = 0; f < 2; ++f)
#pragma unroll
        for (int h = 0; h < 2; ++h)
            acc[f][h] = (f32x4){0.f, 0.f, 0.f, 0.f};

    // per-lane global chunk geometry (shared by all stage calls)
    // c = it*512 + tid; m = c>>4; kb = (c&15) ^ (m&15)
    int cm[4], ckb[4];
#pragma unroll
    for (int it = 0; it < 4; ++it) {
        int c = it * 512 + tid;
        cm[it]  = c >> 4;
        ckb[it] = (c & 15) ^ (cm[it] & 15);
    }
    const int wave_lds = w * 64 * 8;   // halfs: (w*64 lanes)*8 halfs per lane

    // ---- prime group g0: async A stage into buf 0 + qweight/scale regs ----
#pragma unroll
    for (int it = 0; it < 4; ++it)
        load_lds16(xh + (size_t)cm[it] * K_DIM + g0 * GS + ckb[it] * 8,
                   &As[0][it * 512 * 8 + wave_lds]);
    unsigned qwn[8];
    float scn[2], zcn[2];
#pragma unroll
    for (int kk = 0; kk < 4; ++kk)
#pragma unroll
        for (int h = 0; h < 2; ++h)
            qwn[kk * 2 + h] = (unsigned)qweight[(size_t)(g0 * 16 + kk * 4 + q) * N_DIM + ncol[h]];
#pragma unroll
    for (int h = 0; h < 2; ++h) {
        scn[h] = scales[(size_t)g0 * N_DIM + ncol[h]];
        zcn[h] = zst[(size_t)g0 * N_DIM + ncol[h]];
    }

    int p = 0;
    for (int g = 0; g < GPB; ++g) {
        // rotate qweight/scale regs
        unsigned qw[8];
        float sc[2], zc[2];
#pragma unroll
        for (int i = 0; i < 8; ++i) qw[i] = qwn[i];
#pragma unroll
        for (int h = 0; h < 2; ++h) { sc[h] = scn[h]; zc[h] = zcn[h]; }

        __syncthreads();   // A(g) resident in As[p] (compiler drains vmcnt here)

        if (g + 1 < GPB) { // issue next group's async loads NOW, overlap compute
            int gn = g0 + g + 1;
#pragma unroll
            for (int it = 0; it < 4; ++it)
                load_lds16(xh + (size_t)cm[it] * K_DIM + gn * GS + ckb[it] * 8,
                           &As[p ^ 1][it * 512 * 8 + wave_lds]);
#pragma unroll
            for (int kk = 0; kk < 4; ++kk)
#pragma unroll
                for (int h = 0; h < 2; ++h)
                    qwn[kk * 2 + h] = (unsigned)qweight[(size_t)(gn * 16 + kk * 4 + q) * N_DIM + ncol[h]];
#pragma unroll
            for (int h = 0; h < 2; ++h) {
                scn[h] = scales[(size_t)gn * N_DIM + ncol[h]];
                zcn[h] = zst[(size_t)gn * N_DIM + ncol[h]];
            }
        }

        // per-(group,h) dequant constants: S2={s, s/16}, Z2={-z1, -z1}
        half2t S2[2], Z2[2];
#pragma unroll
        for (int h = 0; h < 2; ++h) {
            float s = sc[h], z1 = zc[h];
            S2[h][0] = (_Float16)s;
            S2[h][1] = (_Float16)(s * 0.0625f);
            Z2[h][0] = (_Float16)(-z1);
            Z2[h][1] = (_Float16)(-z1);
        }

#pragma unroll
        for (int kk = 0; kk < 4; ++kk) {
            half8 bf[2];
#pragma unroll
            for (int h = 0; h < 2; ++h)
                bf[h] = dequant8(qw[kk * 2 + h], S2[h], Z2[h]);
#pragma unroll
            for (int f = 0; f < 2; ++f) {
                int m   = wy * 32 + f * 16 + lr;
                int kb2 = (kk * 4 + q) ^ lr;     // m&15 == lr
                half8 af = *(const half8*)(&As[p][m * 128 + kb2 * 8]);
#pragma unroll
                for (int h = 0; h < 2; ++h)
                    acc[f][h] = __builtin_amdgcn_mfma_f32_16x16x32_f16(af, bf[h], acc[f][h], 0, 0, 0);
            }
        }
        p ^= 1;
    }

    // ---- epilogue: plain coalesced stores to this split's partial buffer ----
    float* po = part + (size_t)blockIdx.y * PART_STRIDE;
#pragma unroll
    for (int f = 0; f < 2; ++f) {
        int mrow = wy * 32 + f * 16 + q * 4;
#pragma unroll
        for (int h = 0; h < 2; ++h)
#pragma unroll
            for (int r = 0; r < 4; ++r)
                po[(size_t)(mrow + r) * N_DIM + ncol[h]] = acc[f][h][r];
    }
}

// ---------------- reduce: out = bias + sum_s part[s] ----------------
__global__ void k_reduce(const float* __restrict__ part, const float* __restrict__ bias,
                         float* __restrict__ out) {
    int i = (blockIdx.x * 256 + threadIdx.x) * 4;   // 1376 blocks: 128*11008 exact
    int m = i / N_DIM;
    int n = i - m * N_DIM;                           // N_DIM%4==0 -> n%4==0
    f32x4 s = *(const f32x4*)(bias + n);
#pragma unroll
    for (int sp = 0; sp < SPLIT; ++sp)
        s += *(const f32x4*)(part + sp * PART_STRIDE + i);
    *(f32x4*)(out + i) = s;
}

extern "C" void kernel_launch(void* const* d_in, const int* in_sizes, int n_in,
                              void* d_out, int out_size, void* d_ws, size_t ws_size,
                              hipStream_t stream) {
    const float* x       = (const float*)d_in[0];
    const int*   qweight = (const int*)d_in[1];
    const int*   qzeros  = (const int*)d_in[2];
    const float* scales  = (const float*)d_in[3];
    const float* bias    = (const float*)d_in[4];
    // d_in[5] = g_idx, affine by construction -> unused

    char* ws = (char*)d_ws;
    _Float16* xh   = (_Float16*)ws;                              // 1,048,576 B
    float*    zst  = (float*)(ws + 1048576);                     // 1,409,024 B
    float*    part = (float*)(ws + 1048576 + 1409024);           // 4 x 5,636,096 B

    k_prep  <<<dim3(1888),            dim3(256), 0, stream>>>(x, qzeros, scales, xh, zst);
    k_gemm  <<<dim3(N_DIM/64, SPLIT), dim3(512), 0, stream>>>(xh, qweight, scales, zst, part);
    k_reduce<<<dim3(1376),            dim3(256), 0, stream>>>(part, bias, (float*)d_out);
}

// Round 6
// 103.613 us; speedup vs baseline: 2.5667x; 1.0412x over previous
//
#include <hip/hip_runtime.h>
#include <stdint.h>

// GPTQ 4-bit fused dequant-GEMM, MI355X gfx950.  Round 6.
// M=128, K=4096, N=11008, group=128, g_idx[k]=k>>7 (affine).
//
// R5 fixed the scratch catastrophe (SROA-safe dequant + async global_load_lds
// dbuf): 200.8 -> 107.9 us total; k_gemm fell out of the top-5 (all harness
// 0xAA ws-fills @42us, a fixed ~60us of every measurement).  R6 attacks the
// VALU:MFMA imbalance (was 96 dequant-VALU vs 78 MFMA cyc per wave-group):
//  * wave retile 32x32 -> 64m x 32n (f=4): B-fragment reuse 2x -> 4x,
//    dequant VALU per MAC halved, qweight load duplication per block halved.
//  * group's kk-range split across wave pairs: w = (kh<<2)|(wy<<1)|wx;
//    kh=0 does kk{0,1}, kh=1 does kk{2,3}.  Pair (w, w^4) merges accs via a
//    32KB LDS exchange after the K-loop (reuses the A buffer post-barrier).
//  * block still 512 thr / 64KB LDS dbuf -> 2 blocks/CU, 4 waves/SIMD.
// Unchanged: split-K x4 grid (172,4), f32 partials + k_reduce(bias), k_prep,
// exact-cancellation f16 magic dequant, XOR-swizzled async A staging.

#define M_DIM 128
#define K_DIM 4096
#define N_DIM 11008
#define GS    128
#define NG    32
#define SPLIT 4
#define GPB   (NG / SPLIT)   // 8 groups per block
#define PART_STRIDE ((size_t)M_DIM * N_DIM)

typedef _Float16 half8  __attribute__((ext_vector_type(8)));
typedef _Float16 half2t __attribute__((ext_vector_type(2)));
typedef _Float16 half4t __attribute__((ext_vector_type(4)));
typedef float    f32x4  __attribute__((ext_vector_type(4)));

// ---------------- prep: blocks 0..511 cvt x->f16; 512..1887 zs=(z+1)*s ----
__global__ void k_prep(const float* __restrict__ x, const int* __restrict__ qzeros,
                       const float* __restrict__ scales,
                       _Float16* __restrict__ xh, float* __restrict__ zs) {
    int b = blockIdx.x, tid = threadIdx.x;
    if (b < 512) {                                   // 512*256*4 == 524288 exact
        int i = (b * 256 + tid) * 4;
        float4 v = *(const float4*)(x + i);
        half4t o;
        o[0] = (_Float16)v.x; o[1] = (_Float16)v.y;
        o[2] = (_Float16)v.z; o[3] = (_Float16)v.w;
        *(half4t*)(xh + i) = o;
    } else {                                         // 1376 blocks: 32 g x 43 nb
        b -= 512;
        int g = b / 43;
        int n = (b - g * 43) * 256 + tid;            // 43*256 == 11008 exact
        unsigned qz = (unsigned)qzeros[g * (N_DIM / 8) + (n >> 3)];
        float z = (float)((qz >> ((n & 7) * 4)) & 15u) + 1.0f;
        zs[g * N_DIM + n] = z * scales[g * N_DIM + n];
    }
}

// async 16B/lane global->LDS; lds base wave-uniform, lane i -> base + i*16.
__device__ __forceinline__ void load_lds16(const void* g, void* l) {
    __builtin_amdgcn_global_load_lds(
        (const __attribute__((address_space(1))) unsigned int*)g,
        (__attribute__((address_space(3))) unsigned int*)l, 16, 0, 0);
}

// nibble pair p (nibbles 2p, 2p+1) of q -> two f16 weights:
//  t  = {0x6400|nib_lo, 0x6400|nib_hi<<4} = {1024+q_lo, 1024+16*q_hi}
//  qf = t - 1024                  (EXACT in f16: integers <= 2048)
//  w  = fma(qf, {s, s/16}, {-z1}) where z1 = (z+1)*s
// No pointer casts: pure vector ops, SROA-safe (scratch regression guard).
__device__ __forceinline__ half8 dequant8(unsigned q, half2t S2, half2t Z2) {
    const half2t BIAS = __builtin_bit_cast(half2t, 0x64006400u);
    half2t w[4];
#pragma unroll
    for (int p = 0; p < 4; ++p) {
        unsigned r = __builtin_amdgcn_perm(q, q, 0x00010001u * (unsigned)p); // byte p -> bytes 0,2
        unsigned t = (r & 0x00F0000Fu) | 0x64006400u;                        // v_and_or_b32
        w[p] = __builtin_elementwise_fma(__builtin_bit_cast(half2t, t) - BIAS, S2, Z2);
    }
    half4t lo = __builtin_shufflevector(w[0], w[1], 0, 1, 2, 3);
    half4t hi = __builtin_shufflevector(w[2], w[3], 0, 1, 2, 3);
    return __builtin_shufflevector(lo, hi, 0, 1, 2, 3, 4, 5, 6, 7);
}

// ---------------- main fused kernel ----------------
__global__ __launch_bounds__(512, 4)
void k_gemm(const _Float16* __restrict__ xh,     // [128][4096] f16
            const int*      __restrict__ qweight,// [512][11008] int32
            const float*    __restrict__ scales, // [32][11008]
            const float*    __restrict__ zst,    // [32][11008] (z+1)*s
            float*          __restrict__ part)   // [SPLIT][128][11008] partials
{
    // Double-buffered A tile: logical (m,kb) of buffer b at
    //   As[b][m*128 + (kb ^ (m&15))*8]   (halfs)
    // Staged so chunk c = it*512+tid lands at byte offset c*16.
    __shared__ _Float16 As[2][128 * 128];   // 2 x 32 KB

    const int tid  = threadIdx.x;
    const int lane = tid & 63;
    const int w    = tid >> 6;    // 0..7
    const int wx   = w & 1;        // n offset 32*wx
    const int wy   = (w >> 1) & 1; // m offset 64*wy
    const int kh   = w >> 2;       // kk-half: kh=0 -> kk{0,1}, kh=1 -> kk{2,3}
    const int q    = lane >> 4;    // quad
    const int lr   = lane & 15;

    const int n0 = blockIdx.x * 64;
    const int g0 = blockIdx.y * GPB;
    int ncol[2] = { n0 + wx * 32 + lr, n0 + wx * 32 + lr + 16 };

    f32x4 acc[4][2];
#pragma unroll
    for (int f = 0; f < 4; ++f)
#pragma unroll
        for (int h = 0; h < 2; ++h)
            acc[f][h] = (f32x4){0.f, 0.f, 0.f, 0.f};

    // per-lane staging geometry: c = it*512 + tid; m=c>>4; kb=(c&15)^(m&15)
    int cm[4], ckb[4];
#pragma unroll
    for (int it = 0; it < 4; ++it) {
        int c = it * 512 + tid;
        cm[it]  = c >> 4;
        ckb[it] = (c & 15) ^ (cm[it] & 15);
    }
    const int wave_lds = w * 64 * 8;   // halfs

    // ---- prime group g0 ----
#pragma unroll
    for (int it = 0; it < 4; ++it)
        load_lds16(xh + (size_t)cm[it] * K_DIM + g0 * GS + ckb[it] * 8,
                   &As[0][it * 512 * 8 + wave_lds]);
    unsigned qwn[4];
    float scn[2], zcn[2];
#pragma unroll
    for (int t = 0; t < 2; ++t)
#pragma unroll
        for (int h = 0; h < 2; ++h)
            qwn[t * 2 + h] = (unsigned)qweight[(size_t)(g0 * 16 + (kh * 2 + t) * 4 + q) * N_DIM + ncol[h]];
#pragma unroll
    for (int h = 0; h < 2; ++h) {
        scn[h] = scales[(size_t)g0 * N_DIM + ncol[h]];
        zcn[h] = zst[(size_t)g0 * N_DIM + ncol[h]];
    }

    int p = 0;
    for (int g = 0; g < GPB; ++g) {
        unsigned qw[4];
        float sc[2], zc[2];
#pragma unroll
        for (int i = 0; i < 4; ++i) qw[i] = qwn[i];
#pragma unroll
        for (int h = 0; h < 2; ++h) { sc[h] = scn[h]; zc[h] = zcn[h]; }

        __syncthreads();   // A(g) resident in As[p]

        if (g + 1 < GPB) { // next group's async loads in flight under compute
            int gn = g0 + g + 1;
#pragma unroll
            for (int it = 0; it < 4; ++it)
                load_lds16(xh + (size_t)cm[it] * K_DIM + gn * GS + ckb[it] * 8,
                           &As[p ^ 1][it * 512 * 8 + wave_lds]);
#pragma unroll
            for (int t = 0; t < 2; ++t)
#pragma unroll
                for (int h = 0; h < 2; ++h)
                    qwn[t * 2 + h] = (unsigned)qweight[(size_t)(gn * 16 + (kh * 2 + t) * 4 + q) * N_DIM + ncol[h]];
#pragma unroll
            for (int h = 0; h < 2; ++h) {
                scn[h] = scales[(size_t)gn * N_DIM + ncol[h]];
                zcn[h] = zst[(size_t)gn * N_DIM + ncol[h]];
            }
        }

        half2t S2[2], Z2[2];
#pragma unroll
        for (int h = 0; h < 2; ++h) {
            float s = sc[h], z1 = zc[h];
            S2[h][0] = (_Float16)s;
            S2[h][1] = (_Float16)(s * 0.0625f);
            Z2[h][0] = (_Float16)(-z1);
            Z2[h][1] = (_Float16)(-z1);
        }

#pragma unroll
        for (int t = 0; t < 2; ++t) {
            const int kk = kh * 2 + t;
            half8 bf[2];
#pragma unroll
            for (int h = 0; h < 2; ++h)
                bf[h] = dequant8(qw[t * 2 + h], S2[h], Z2[h]);
#pragma unroll
            for (int f = 0; f < 4; ++f) {
                int m   = wy * 64 + f * 16 + lr;
                int kb2 = (kk * 4 + q) ^ lr;     // m&15 == lr
                half8 af = *(const half8*)(&As[p][m * 128 + kb2 * 8]);
#pragma unroll
                for (int h = 0; h < 2; ++h)
                    acc[f][h] = __builtin_amdgcn_mfma_f32_16x16x32_f16(af, bf[h], acc[f][h], 0, 0, 0);
            }
        }
        p ^= 1;
    }

    // ---- pair reduction (w, w^4) through LDS, then store partials ----
    __syncthreads();                       // all A reads done; LDS reusable
    float* red = (float*)&As[0][0];        // 32 KB: 4 pairs x 8 KB
    const int pid = w & 3;
    if (w >= 4) {
#pragma unroll
        for (int f = 0; f < 4; ++f)
#pragma unroll
            for (int h = 0; h < 2; ++h)
                *(f32x4*)(red + pid * 2048 + (f * 2 + h) * 256 + lane * 4) = acc[f][h];
    }
    __syncthreads();
    if (w < 4) {
        float* po = part + (size_t)blockIdx.y * PART_STRIDE;
#pragma unroll
        for (int f = 0; f < 4; ++f) {
            int mrow = wy * 64 + f * 16 + q * 4;
#pragma unroll
            for (int h = 0; h < 2; ++h) {
                f32x4 o = acc[f][h] + *(const f32x4*)(red + pid * 2048 + (f * 2 + h) * 256 + lane * 4);
#pragma unroll
                for (int r = 0; r < 4; ++r)
                    po[(size_t)(mrow + r) * N_DIM + ncol[h]] = o[r];
            }
        }
    }
}

// ---------------- reduce: out = bias + sum_s part[s] ----------------
__global__ void k_reduce(const float* __restrict__ part, const float* __restrict__ bias,
                         float* __restrict__ out) {
    int i = (blockIdx.x * 256 + threadIdx.x) * 4;   // 1376 blocks: 128*11008 exact
    int m = i / N_DIM;
    int n = i - m * N_DIM;                           // N_DIM%4==0 -> n%4==0
    f32x4 s = *(const f32x4*)(bias + n);
#pragma unroll
    for (int sp = 0; sp < SPLIT; ++sp)
        s += *(const f32x4*)(part + sp * PART_STRIDE + i);
    *(f32x4*)(out + i) = s;
}

extern "C" void kernel_launch(void* const* d_in, const int* in_sizes, int n_in,
                              void* d_out, int out_size, void* d_ws, size_t ws_size,
                              hipStream_t stream) {
    const float* x       = (const float*)d_in[0];
    const int*   qweight = (const int*)d_in[1];
    const int*   qzeros  = (const int*)d_in[2];
    const float* scales  = (const float*)d_in[3];
    const float* bias    = (const float*)d_in[4];
    // d_in[5] = g_idx, affine by construction -> unused

    char* ws = (char*)d_ws;
    _Float16* xh   = (_Float16*)ws;                              // 1,048,576 B
    float*    zst  = (float*)(ws + 1048576);                     // 1,409,024 B
    float*    part = (float*)(ws + 1048576 + 1409024);           // 4 x 5,636,096 B

    k_prep  <<<dim3(1888),            dim3(256), 0, stream>>>(x, qzeros, scales, xh, zst);
    k_gemm  <<<dim3(N_DIM/64, SPLIT), dim3(512), 0, stream>>>(xh, qweight, scales, zst, part);
    k_reduce<<<dim3(1376),            dim3(256), 0, stream>>>(part, bias, (float*)d_out);
}